// Round 11
// baseline (20856.931 us; speedup 1.0000x reference)
//
#include <hip/hip_runtime.h>

typedef _Float16 f16;
typedef f16 f16x2 __attribute__((ext_vector_type(2)));
typedef f16 f16x4 __attribute__((ext_vector_type(4)));
typedef f16 f16x8 __attribute__((ext_vector_type(8)));
typedef float f32x4 __attribute__((ext_vector_type(4)));
typedef unsigned int u32;
typedef unsigned short u16;
typedef unsigned long long u64;

#define R 4096
#define IN_DIM 256
#define T_STEPS 4096
#define NBLK 128
#define TPB 1024
#define WPB 16
#define RPW 2                      // rows per wave
#define RPB (WPB * RPW)            // 32 rows per block
#define GPB (RPB / 2)              // 16 granules per block

// ---- W f32 -> fp16 conversion (re-run every call; deterministic) ----
__global__ void wconv_kernel(const float* __restrict__ W, f16* __restrict__ Wh) {
    size_t i = ((size_t)blockIdx.x * 256 + threadIdx.x) * 4;
    f32x4 v = *(const f32x4*)(W + i);
    f16x4 o = { (f16)v.x, (f16)v.y, (f16)v.z, (f16)v.w };
    *(f16x4*)(Wh + i) = o;
}

// ---- persistent scan: 128 blocks x 16 waves, 2 rows/wave.
// BARRIER-FREE step loop: each wave stages its 256-row slice of h into LDS
// and sets a tagged per-wave flag; consumers compute the dot chunk-by-chunk
// behind the flags, overlapping compute with granule arrival. ----
__global__ __launch_bounds__(TPB) void esn_kernel(
    const float* __restrict__ x,      // [T][256]
    const float* __restrict__ Win,    // [R][256]
    const f16*   __restrict__ W,      // [R][R] fp16
    u64* hg0, u64* hg1,               // [R/2] tagged granules, double-buffered
    const float* __restrict__ Wout,   // [256][R]
    const float* __restrict__ bias,   // [256]
    float* __restrict__ out)          // [256]
{
    __shared__ f16   h_lds[2][R];     // 16 KB, parity double-buffered
    __shared__ u32   cflag[2][WPB];   // tagged per-parity per-wave stage flags
    __shared__ u32   red_tag[RPB];    // tagged LDS relay words (32)
    __shared__ float red_f[WPB];      // epilogue reduction

    const int tid  = threadIdx.x;
    const int b    = blockIdx.x;
    const int wave = tid >> 6;
    const int lane = tid & 63;

    if (tid < RPB) red_tag[tid] = 0;       // LDS undefined across launches
    if (tid < 2 * WPB) ((u32*)cflag)[tid] = 0;

    // one-time preload: 2 W rows + 2 Win fragments (sourcing is off the
    // critical path -- R8/R9 established compute is fully hidden)
    f16x8 wreg0[8], wreg1[8];
    {
        const f16* wrow0 = W + (size_t)(b * RPB + wave * RPW + 0) * R;
        const f16* wrow1 = W + (size_t)(b * RPB + wave * RPW + 1) * R;
#pragma unroll
        for (int c = 0; c < 8; ++c) {
            wreg0[c] = *(const f16x8*)(wrow0 + (c * 64 + lane) * 8);
            wreg1[c] = *(const f16x8*)(wrow1 + (c * 64 + lane) * 8);
        }
    }
    const f32x4 winreg0 = *(const f32x4*)(Win + (size_t)(b * RPB + wave * RPW + 0) * IN_DIM + lane * 4);
    const f32x4 winreg1 = *(const f32x4*)(Win + (size_t)(b * RPB + wave * RPW + 1) * IN_DIM + lane * 4);
    __syncthreads();

    for (int t = 0; t < T_STEPS; ++t) {
        const int p = t & 1;
        const u64* g_in  = p ? hg1 : hg0;
        u64*       g_out = p ? hg0 : hg1;

        // x fragment straight from global (L3 broadcast); issue before poll
        const f32x4 xf = *(const f32x4*)(x + (size_t)t * IN_DIM + lane * 4);

        // ---- poll own granules (rows 4tid..4tid+3), stage, flag ----
        {
            const u64* gp = g_in + (size_t)tid * 2;
            const u64 tt = (u64)(u32)t;
            u64 g0 = 0, g1 = 0;
            bool v0 = false, v1 = false;
            int spin = 0;
            for (;;) {
                if (!v0) { g0 = __hip_atomic_load(gp,     __ATOMIC_RELAXED, __HIP_MEMORY_SCOPE_AGENT); v0 = (g0 >> 48) == tt; }
                if (!v1) { g1 = __hip_atomic_load(gp + 1, __ATOMIC_RELAXED, __HIP_MEMORY_SCOPE_AGENT); v1 = (g1 >> 48) == tt; }
                if (v0 & v1) break;
                if (++spin > 48) __builtin_amdgcn_s_sleep(1);
            }
            u32* hl = (u32*)h_lds[p];
            hl[tid * 2 + 0] = (u32)g0;   // rows 4tid, 4tid+1 (packed f16x2)
            hl[tid * 2 + 1] = (u32)g1;   // rows 4tid+2, 4tid+3
        }
        // release: orders this wave's LDS h-writes before the flag
        if (lane == 0)
            __hip_atomic_store(&cflag[p][wave], (u32)(t + 1),
                               __ATOMIC_RELEASE, __HIP_MEMORY_SCOPE_WORKGROUP);

        // ---- chunked dot behind flags, rotated start to spread the tail ----
        float a00 = 0.f, a01 = 0.f, a02 = 0.f, a03 = 0.f;
        float a10 = 0.f, a11 = 0.f, a12 = 0.f, a13 = 0.f;
        const int c0 = wave & 7;
#pragma unroll
        for (int i = 0; i < 8; ++i) {
            const int c = (c0 + i) & 7;
            // wait: chunk c (rows 512c..512c+511) staged by waves 2c, 2c+1
            {
                const u32 need = (u32)(t + 1);
                int sp = 0;
                for (;;) {
                    u32 f0 = __hip_atomic_load(&cflag[p][2 * c],     __ATOMIC_ACQUIRE, __HIP_MEMORY_SCOPE_WORKGROUP);
                    u32 f1 = __hip_atomic_load(&cflag[p][2 * c + 1], __ATOMIC_ACQUIRE, __HIP_MEMORY_SCOPE_WORKGROUP);
                    if ((f0 >= need) & (f1 >= need)) break;
                    if (++sp > 64) __builtin_amdgcn_s_sleep(1);
                }
            }
            const f16x8 hv = *(const f16x8*)(&h_lds[p][(c * 64 + lane) * 8]);
            const f16x2 h0 = { hv[0], hv[1] }, h1 = { hv[2], hv[3] };
            const f16x2 h2 = { hv[4], hv[5] }, h3 = { hv[6], hv[7] };
            {
                const f16x2 w0 = { wreg0[c][0], wreg0[c][1] }, w1 = { wreg0[c][2], wreg0[c][3] };
                const f16x2 w2 = { wreg0[c][4], wreg0[c][5] }, w3 = { wreg0[c][6], wreg0[c][7] };
                a00 = __builtin_amdgcn_fdot2(w0, h0, a00, false);
                a01 = __builtin_amdgcn_fdot2(w1, h1, a01, false);
                a02 = __builtin_amdgcn_fdot2(w2, h2, a02, false);
                a03 = __builtin_amdgcn_fdot2(w3, h3, a03, false);
            }
            {
                const f16x2 w0 = { wreg1[c][0], wreg1[c][1] }, w1 = { wreg1[c][2], wreg1[c][3] };
                const f16x2 w2 = { wreg1[c][4], wreg1[c][5] }, w3 = { wreg1[c][6], wreg1[c][7] };
                a10 = __builtin_amdgcn_fdot2(w0, h0, a10, false);
                a11 = __builtin_amdgcn_fdot2(w1, h1, a11, false);
                a12 = __builtin_amdgcn_fdot2(w2, h2, a12, false);
                a13 = __builtin_amdgcn_fdot2(w3, h3, a13, false);
            }
        }
        float acc0 = (a00 + a01) + (a02 + a03);
        float acc1 = (a10 + a11) + (a12 + a13);
        acc0 = fmaf(winreg0.x, xf.x, acc0); acc0 = fmaf(winreg0.y, xf.y, acc0);
        acc0 = fmaf(winreg0.z, xf.z, acc0); acc0 = fmaf(winreg0.w, xf.w, acc0);
        acc1 = fmaf(winreg1.x, xf.x, acc1); acc1 = fmaf(winreg1.y, xf.y, acc1);
        acc1 = fmaf(winreg1.z, xf.z, acc1); acc1 = fmaf(winreg1.w, xf.w, acc1);
#pragma unroll
        for (int off = 32; off > 0; off >>= 1) {
            acc0 += __shfl_xor(acc0, off, 64);
            acc1 += __shfl_xor(acc1, off, 64);
        }

        // ---- tagged LDS relay: lanes 0,1 post rows 2w,2w+1 ----
        {
            const float v = (lane == 0) ? acc0 : acc1;
            if (lane < 2) {
                f16 hf = (f16)tanhf(v);
                u16 bits;
                __builtin_memcpy(&bits, &hf, 2);
                __hip_atomic_store(&red_tag[wave * 2 + lane],
                                   ((u32)(t + 1) << 16) | (u32)bits,
                                   __ATOMIC_RELEASE, __HIP_MEMORY_SCOPE_WORKGROUP);
            }
        }

        // ---- wave 15: gather 32 relay words, pack 16 granules, ONE burst ----
        if (wave == WPB - 1) {
            u32 myw = 0;
            if (lane < RPB) {
                int sp = 0;
                do {
                    myw = __hip_atomic_load(&red_tag[lane], __ATOMIC_ACQUIRE,
                                            __HIP_MEMORY_SCOPE_WORKGROUP);
                    if (++sp > 64) __builtin_amdgcn_s_sleep(1);
                } while ((myw >> 16) != (u32)(t + 1));
            }
            const u32 wa = (u32)__shfl((int)myw, lane * 2,     64);
            const u32 wb = (u32)__shfl((int)myw, lane * 2 + 1, 64);
            if (lane < GPB) {
                const u64 g = ((u64)(u32)(t + 1) << 48)
                            | ((u64)(wb & 0xffffu) << 16)
                            | ((u64)(wa & 0xffffu));
                __hip_atomic_store(g_out + b * GPB + lane, g,
                                   __ATOMIC_RELAXED, __HIP_MEMORY_SCOPE_AGENT);
            }
        }
        // no barrier: tagged flags + parity double-buffering gate all reuse
    }

    // ---- epilogue: poll h_T (tag = T_STEPS, parity 0), 2 outputs/block ----
    {
        const u64* gp = hg0 + (size_t)tid * 2;
        const u64 tt = (u64)(u32)T_STEPS;
        u64 g0, g1;
        for (;;) {
            g0 = __hip_atomic_load(gp,     __ATOMIC_RELAXED, __HIP_MEMORY_SCOPE_AGENT);
            g1 = __hip_atomic_load(gp + 1, __ATOMIC_RELAXED, __HIP_MEMORY_SCOPE_AGENT);
            if (((g0 >> 48) == tt) & ((g1 >> 48) == tt)) break;
            __builtin_amdgcn_s_sleep(1);
        }
        u32* hl = (u32*)h_lds[0];
        hl[tid * 2 + 0] = (u32)g0;
        hl[tid * 2 + 1] = (u32)g1;
    }
    __syncthreads();
#pragma unroll
    for (int oj = 0; oj < 2; ++oj) {
        const int j = b * 2 + oj;
        const float* worow = Wout + (size_t)j * R;
        const f32x4 wv = *(const f32x4*)(worow + tid * 4);
        const f16* hf = h_lds[0];
        float acc = wv.x * (float)hf[tid * 4 + 0]
                  + wv.y * (float)hf[tid * 4 + 1]
                  + wv.z * (float)hf[tid * 4 + 2]
                  + wv.w * (float)hf[tid * 4 + 3];
#pragma unroll
        for (int off = 32; off > 0; off >>= 1)
            acc += __shfl_xor(acc, off, 64);
        if (lane == 0) red_f[wave] = acc;
        __syncthreads();
        if (tid == 0) {
            float s = bias[j];
#pragma unroll
            for (int w = 0; w < WPB; ++w) s += red_f[w];
            out[j] = s;
        }
        __syncthreads();  // red_f reuse guard for oj=1
    }
}

extern "C" void kernel_launch(void* const* d_in, const int* in_sizes, int n_in,
                              void* d_out, int out_size, void* d_ws, size_t ws_size,
                              hipStream_t stream) {
    const float* x    = (const float*)d_in[0];
    const float* Win  = (const float*)d_in[1];
    const float* W    = (const float*)d_in[2];
    const float* Wout = (const float*)d_in[3];
    const float* bias = (const float*)d_in[4];
    float* out = (float*)d_out;

    char* ws = (char*)d_ws;
    u64* hg0 = (u64*)ws;                   // 16 KB tagged granules, parity 0
    u64* hg1 = (u64*)(ws + 16384);         // 16 KB tagged granules, parity 1
    f16* Wh  = (f16*)(ws + 65536);         // 32 MB fp16 W

    // zero both granule buffers: h_0 = 0 with tag 0 comes for free
    hipMemsetAsync(ws, 0, 65536, stream);

    wconv_kernel<<<(R * (size_t)R) / (256 * 4), 256, 0, stream>>>(W, Wh);
    esn_kernel<<<NBLK, TPB, 0, stream>>>(x, Win, Wh, hg0, hg1,
                                         Wout, bias, out);
}

// Round 12
// 15462.938 us; speedup vs baseline: 1.3488x; 1.3488x over previous
//
#include <hip/hip_runtime.h>

typedef _Float16 f16;
typedef f16 f16x2 __attribute__((ext_vector_type(2)));
typedef f16 f16x4 __attribute__((ext_vector_type(4)));
typedef f16 f16x8 __attribute__((ext_vector_type(8)));
typedef float f32x4 __attribute__((ext_vector_type(4)));
typedef unsigned int u32;
typedef unsigned short u16;
typedef unsigned long long u64;

#define R 4096
#define IN_DIM 256
#define T_STEPS 4096
#define NBLK 128
#define TPB 1024
#define WPB 16
#define RPW 2                      // rows per wave
#define RPB (WPB * RPW)            // 32 rows per block
#define GPB (RPB / 2)              // 16 granules per block

// ---- W f32 -> fp16 conversion (re-run every call; deterministic) ----
__global__ void wconv_kernel(const float* __restrict__ W, f16* __restrict__ Wh) {
    size_t i = ((size_t)blockIdx.x * 256 + threadIdx.x) * 4;
    f32x4 v = *(const f32x4*)(W + i);
    f16x4 o = { (f16)v.x, (f16)v.y, (f16)v.z, (f16)v.w };
    *(f16x4*)(Wh + i) = o;
}

// ---- persistent scan: 128 blocks x 16 waves, 2 rows/wave.
// Barrier-free chunk-pipelined step: waves stage their h slice + set tagged
// LDS flags; dot consumes chunks 0..7 in COMPILE-TIME order behind flags
// (R11 retry minus the runtime-register-indexing bug). ----
__global__ __launch_bounds__(TPB) void esn_kernel(
    const float* __restrict__ x,      // [T][256]
    const float* __restrict__ Win,    // [R][256]
    const f16*   __restrict__ W,      // [R][R] fp16
    u64* hg0, u64* hg1,               // [R/2] tagged granules, double-buffered
    const float* __restrict__ Wout,   // [256][R]
    const float* __restrict__ bias,   // [256]
    float* __restrict__ out)          // [256]
{
    __shared__ f16   h_lds[2][R];     // 16 KB, parity double-buffered
    __shared__ u32   cflag[2][WPB];   // tagged per-parity per-wave stage flags
    __shared__ u32   red_tag[RPB];    // tagged LDS relay words (32)
    __shared__ float red_f[WPB];      // epilogue reduction

    const int tid  = threadIdx.x;
    const int b    = blockIdx.x;
    const int wave = tid >> 6;
    const int lane = tid & 63;

    if (tid < RPB) red_tag[tid] = 0;       // LDS undefined across launches
    if (tid < 2 * WPB) ((u32*)cflag)[tid] = 0;

    // one-time preload: 2 W rows + 2 Win fragments (off the critical path)
    f16x8 wreg0[8], wreg1[8];
    {
        const f16* wrow0 = W + (size_t)(b * RPB + wave * RPW + 0) * R;
        const f16* wrow1 = W + (size_t)(b * RPB + wave * RPW + 1) * R;
#pragma unroll
        for (int c = 0; c < 8; ++c) {
            wreg0[c] = *(const f16x8*)(wrow0 + (c * 64 + lane) * 8);
            wreg1[c] = *(const f16x8*)(wrow1 + (c * 64 + lane) * 8);
        }
    }
    const f32x4 winreg0 = *(const f32x4*)(Win + (size_t)(b * RPB + wave * RPW + 0) * IN_DIM + lane * 4);
    const f32x4 winreg1 = *(const f32x4*)(Win + (size_t)(b * RPB + wave * RPW + 1) * IN_DIM + lane * 4);
    __syncthreads();

    for (int t = 0; t < T_STEPS; ++t) {
        const int p = t & 1;
        const u64* g_in  = p ? hg1 : hg0;
        u64*       g_out = p ? hg0 : hg1;

        // x fragment straight from global (L1/L3 broadcast)
        const f32x4 xf = *(const f32x4*)(x + (size_t)t * IN_DIM + lane * 4);

        // ---- poll own granules (rows 4tid..4tid+3), stage, flag ----
        {
            const u64* gp = g_in + (size_t)tid * 2;
            const u64 tt = (u64)(u32)t;
            u64 g0 = 0, g1 = 0;
            bool v0 = false, v1 = false;
            int spin = 0;
            for (;;) {
                if (!v0) { g0 = __hip_atomic_load(gp,     __ATOMIC_RELAXED, __HIP_MEMORY_SCOPE_AGENT); v0 = (g0 >> 48) == tt; }
                if (!v1) { g1 = __hip_atomic_load(gp + 1, __ATOMIC_RELAXED, __HIP_MEMORY_SCOPE_AGENT); v1 = (g1 >> 48) == tt; }
                if (v0 & v1) break;
                if (++spin > 48) __builtin_amdgcn_s_sleep(1);
            }
            u32* hl = (u32*)h_lds[p];
            hl[tid * 2 + 0] = (u32)g0;   // rows 4tid, 4tid+1 (packed f16x2)
            hl[tid * 2 + 1] = (u32)g1;   // rows 4tid+2, 4tid+3
        }
        // release: orders this wave's LDS h-writes before the flag
        if (lane == 0)
            __hip_atomic_store(&cflag[p][wave], (u32)(t + 1),
                               __ATOMIC_RELEASE, __HIP_MEMORY_SCOPE_WORKGROUP);

        // ---- chunk-pipelined dot: FIXED order, compile-time indices ----
        float a00 = 0.f, a01 = 0.f, a02 = 0.f, a03 = 0.f;
        float a10 = 0.f, a11 = 0.f, a12 = 0.f, a13 = 0.f;
#pragma unroll
        for (int c = 0; c < 8; ++c) {   // fully unrolled -> c is a constant
            // wait: chunk c (rows 512c..512c+511) staged by waves 2c, 2c+1
            {
                const u32 need = (u32)(t + 1);
                int sp = 0;
                for (;;) {
                    u32 f0 = __hip_atomic_load(&cflag[p][2 * c],     __ATOMIC_ACQUIRE, __HIP_MEMORY_SCOPE_WORKGROUP);
                    u32 f1 = __hip_atomic_load(&cflag[p][2 * c + 1], __ATOMIC_ACQUIRE, __HIP_MEMORY_SCOPE_WORKGROUP);
                    if ((f0 >= need) & (f1 >= need)) break;
                    if (++sp > 64) __builtin_amdgcn_s_sleep(1);
                }
            }
            const f16x8 hv = *(const f16x8*)(&h_lds[p][(c * 64 + lane) * 8]);
            const f16x2 h0 = { hv[0], hv[1] }, h1 = { hv[2], hv[3] };
            const f16x2 h2 = { hv[4], hv[5] }, h3 = { hv[6], hv[7] };
            {
                const f16x2 w0 = { wreg0[c][0], wreg0[c][1] }, w1 = { wreg0[c][2], wreg0[c][3] };
                const f16x2 w2 = { wreg0[c][4], wreg0[c][5] }, w3 = { wreg0[c][6], wreg0[c][7] };
                a00 = __builtin_amdgcn_fdot2(w0, h0, a00, false);
                a01 = __builtin_amdgcn_fdot2(w1, h1, a01, false);
                a02 = __builtin_amdgcn_fdot2(w2, h2, a02, false);
                a03 = __builtin_amdgcn_fdot2(w3, h3, a03, false);
            }
            {
                const f16x2 w0 = { wreg1[c][0], wreg1[c][1] }, w1 = { wreg1[c][2], wreg1[c][3] };
                const f16x2 w2 = { wreg1[c][4], wreg1[c][5] }, w3 = { wreg1[c][6], wreg1[c][7] };
                a10 = __builtin_amdgcn_fdot2(w0, h0, a10, false);
                a11 = __builtin_amdgcn_fdot2(w1, h1, a11, false);
                a12 = __builtin_amdgcn_fdot2(w2, h2, a12, false);
                a13 = __builtin_amdgcn_fdot2(w3, h3, a13, false);
            }
        }
        float acc0 = (a00 + a01) + (a02 + a03);
        float acc1 = (a10 + a11) + (a12 + a13);
        acc0 = fmaf(winreg0.x, xf.x, acc0); acc0 = fmaf(winreg0.y, xf.y, acc0);
        acc0 = fmaf(winreg0.z, xf.z, acc0); acc0 = fmaf(winreg0.w, xf.w, acc0);
        acc1 = fmaf(winreg1.x, xf.x, acc1); acc1 = fmaf(winreg1.y, xf.y, acc1);
        acc1 = fmaf(winreg1.z, xf.z, acc1); acc1 = fmaf(winreg1.w, xf.w, acc1);
#pragma unroll
        for (int off = 32; off > 0; off >>= 1) {
            acc0 += __shfl_xor(acc0, off, 64);
            acc1 += __shfl_xor(acc1, off, 64);
        }

        // ---- tagged LDS relay: lanes 0,1 post rows 2w,2w+1 ----
        {
            const float v = (lane == 0) ? acc0 : acc1;
            if (lane < 2) {
                f16 hf = (f16)tanhf(v);
                u16 bits;
                __builtin_memcpy(&bits, &hf, 2);
                __hip_atomic_store(&red_tag[wave * 2 + lane],
                                   ((u32)(t + 1) << 16) | (u32)bits,
                                   __ATOMIC_RELEASE, __HIP_MEMORY_SCOPE_WORKGROUP);
            }
        }

        // ---- wave 15: gather 32 relay words, pack 16 granules, ONE burst ----
        if (wave == WPB - 1) {
            u32 myw = 0;
            if (lane < RPB) {
                do {
                    myw = __hip_atomic_load(&red_tag[lane], __ATOMIC_ACQUIRE,
                                            __HIP_MEMORY_SCOPE_WORKGROUP);
                } while ((myw >> 16) != (u32)(t + 1));
            }
            const u32 wa = (u32)__shfl((int)myw, lane * 2,     64);
            const u32 wb = (u32)__shfl((int)myw, lane * 2 + 1, 64);
            if (lane < GPB) {
                const u64 g = ((u64)(u32)(t + 1) << 48)
                            | ((u64)(wb & 0xffffu) << 16)
                            | ((u64)(wa & 0xffffu));
                __hip_atomic_store(g_out + b * GPB + lane, g,
                                   __ATOMIC_RELAXED, __HIP_MEMORY_SCOPE_AGENT);
            }
        }
        // no barrier: tagged flags + parity double-buffering gate all reuse
    }

    // ---- epilogue: poll h_T (tag = T_STEPS, parity 0), 2 outputs/block ----
    {
        const u64* gp = hg0 + (size_t)tid * 2;
        const u64 tt = (u64)(u32)T_STEPS;
        u64 g0, g1;
        for (;;) {
            g0 = __hip_atomic_load(gp,     __ATOMIC_RELAXED, __HIP_MEMORY_SCOPE_AGENT);
            g1 = __hip_atomic_load(gp + 1, __ATOMIC_RELAXED, __HIP_MEMORY_SCOPE_AGENT);
            if (((g0 >> 48) == tt) & ((g1 >> 48) == tt)) break;
            __builtin_amdgcn_s_sleep(1);
        }
        u32* hl = (u32*)h_lds[0];
        hl[tid * 2 + 0] = (u32)g0;
        hl[tid * 2 + 1] = (u32)g1;
    }
    __syncthreads();
#pragma unroll
    for (int oj = 0; oj < 2; ++oj) {
        const int j = b * 2 + oj;
        const float* worow = Wout + (size_t)j * R;
        const f32x4 wv = *(const f32x4*)(worow + tid * 4);
        const f16* hf = h_lds[0];
        float acc = wv.x * (float)hf[tid * 4 + 0]
                  + wv.y * (float)hf[tid * 4 + 1]
                  + wv.z * (float)hf[tid * 4 + 2]
                  + wv.w * (float)hf[tid * 4 + 3];
#pragma unroll
        for (int off = 32; off > 0; off >>= 1)
            acc += __shfl_xor(acc, off, 64);
        if (lane == 0) red_f[wave] = acc;
        __syncthreads();
        if (tid == 0) {
            float s = bias[j];
#pragma unroll
            for (int w = 0; w < WPB; ++w) s += red_f[w];
            out[j] = s;
        }
        __syncthreads();  // red_f reuse guard for oj=1
    }
}

extern "C" void kernel_launch(void* const* d_in, const int* in_sizes, int n_in,
                              void* d_out, int out_size, void* d_ws, size_t ws_size,
                              hipStream_t stream) {
    const float* x    = (const float*)d_in[0];
    const float* Win  = (const float*)d_in[1];
    const float* W    = (const float*)d_in[2];
    const float* Wout = (const float*)d_in[3];
    const float* bias = (const float*)d_in[4];
    float* out = (float*)d_out;

    char* ws = (char*)d_ws;
    u64* hg0 = (u64*)ws;                   // 16 KB tagged granules, parity 0
    u64* hg1 = (u64*)(ws + 16384);         // 16 KB tagged granules, parity 1
    f16* Wh  = (f16*)(ws + 65536);         // 32 MB fp16 W

    // zero both granule buffers: h_0 = 0 with tag 0 comes for free
    hipMemsetAsync(ws, 0, 65536, stream);

    wconv_kernel<<<(R * (size_t)R) / (256 * 4), 256, 0, stream>>>(W, Wh);
    esn_kernel<<<NBLK, TPB, 0, stream>>>(x, Win, Wh, hg0, hg1,
                                         Wout, bias, out);
}

// Round 13
// 10928.297 us; speedup vs baseline: 1.9085x; 1.4149x over previous
//
#include <hip/hip_runtime.h>

typedef _Float16 f16;
typedef f16 f16x2 __attribute__((ext_vector_type(2)));
typedef f16 f16x4 __attribute__((ext_vector_type(4)));
typedef f16 f16x8 __attribute__((ext_vector_type(8)));
typedef float f32x4 __attribute__((ext_vector_type(4)));
typedef unsigned int u32;
typedef unsigned short u16;
typedef unsigned long long u64;

#define R 4096
#define IN_DIM 256
#define T_STEPS 4096
#define NBLK 128
#define TPB 1024
#define WPB 16
#define RPW 2                      // rows per wave
#define RPB (WPB * RPW)            // 32 rows per block
#define GPB (RPB / 2)              // 16 granules per block

// ---- W f32 -> fp16 conversion (re-run every call; deterministic) ----
__global__ void wconv_kernel(const float* __restrict__ W, f16* __restrict__ Wh) {
    size_t i = ((size_t)blockIdx.x * 256 + threadIdx.x) * 4;
    f32x4 v = *(const f32x4*)(W + i);
    f16x4 o = { (f16)v.x, (f16)v.y, (f16)v.z, (f16)v.w };
    *(f16x4*)(Wh + i) = o;
}

// ---- persistent scan: 128 blocks x 16 waves, 2 rows/wave (R8 best-known).
// h exchanged as self-validating u64 granules (tag<<48 | 2 f16 rows),
// published as ONE 128B burst per block per step (16 u64 from wave 15). ----
__global__ __launch_bounds__(TPB) void esn_kernel(
    const float* __restrict__ x,      // [T][256]
    const float* __restrict__ Win,    // [R][256]
    const f16*   __restrict__ W,      // [R][R] fp16
    u64* hg0, u64* hg1,               // [R/2] tagged granules, double-buffered
    const float* __restrict__ Wout,   // [256][R]
    const float* __restrict__ bias,   // [256]
    float* __restrict__ out)          // [256]
{
    __shared__ f16   h_lds[2][R];     // 16 KB, parity double-buffered
    __shared__ float x_lds[2][IN_DIM];
    __shared__ u32   red_tag[RPB];    // tagged LDS relay words (32)
    __shared__ float red_f[WPB];      // epilogue reduction

    const int tid  = threadIdx.x;
    const int b    = blockIdx.x;
    const int wave = tid >> 6;
    const int lane = tid & 63;

    if (tid < RPB) red_tag[tid] = 0;  // LDS undefined across launches

    // one-time preload: 2 W rows + 2 Win fragments (sourcing is off the
    // critical path -- R8/R9 established compute is fully hidden)
    f16x8 wreg0[8], wreg1[8];
    {
        const f16* wrow0 = W + (size_t)(b * RPB + wave * RPW + 0) * R;
        const f16* wrow1 = W + (size_t)(b * RPB + wave * RPW + 1) * R;
#pragma unroll
        for (int c = 0; c < 8; ++c) {
            wreg0[c] = *(const f16x8*)(wrow0 + (c * 64 + lane) * 8);
            wreg1[c] = *(const f16x8*)(wrow1 + (c * 64 + lane) * 8);
        }
    }
    const f32x4 winreg0 = *(const f32x4*)(Win + (size_t)(b * RPB + wave * RPW + 0) * IN_DIM + lane * 4);
    const f32x4 winreg1 = *(const f32x4*)(Win + (size_t)(b * RPB + wave * RPW + 1) * IN_DIM + lane * 4);
    __syncthreads();

    for (int t = 0; t < T_STEPS; ++t) {
        const int p = t & 1;
        const u64* g_in  = p ? hg1 : hg0;
        u64*       g_out = p ? hg0 : hg1;

        // issue x[t] fragment load early; latency hides under the poll
        float xv = 0.f;
        if (tid < IN_DIM) xv = x[(size_t)t * IN_DIM + tid];

        // ---- fused poll+load, independent revalidation per granule ----
        {
            const u64* gp = g_in + (size_t)tid * 2;
            const u64 tt = (u64)(u32)t;
            u64 g0 = 0, g1 = 0;
            bool v0 = false, v1 = false;
            for (;;) {
                if (!v0) { g0 = __hip_atomic_load(gp,     __ATOMIC_RELAXED, __HIP_MEMORY_SCOPE_AGENT); v0 = (g0 >> 48) == tt; }
                if (!v1) { g1 = __hip_atomic_load(gp + 1, __ATOMIC_RELAXED, __HIP_MEMORY_SCOPE_AGENT); v1 = (g1 >> 48) == tt; }
                if (v0 & v1) break;
                __builtin_amdgcn_s_sleep(1);
            }
            u32* hl = (u32*)h_lds[p];
            hl[tid * 2 + 0] = (u32)g0;   // rows 4tid, 4tid+1 (packed f16x2)
            hl[tid * 2 + 1] = (u32)g1;   // rows 4tid+2, 4tid+3
        }
        if (tid < IN_DIM) x_lds[p][tid] = xv;
        __syncthreads();  // the ONLY barrier per step

        // ---- 2-row dot: 8 ds_read_b128 + 64 fdot2 (8 chains) ----
        float a00 = 0.f, a01 = 0.f, a02 = 0.f, a03 = 0.f;
        float a10 = 0.f, a11 = 0.f, a12 = 0.f, a13 = 0.f;
#pragma unroll
        for (int c = 0; c < 8; ++c) {
            const f16x8 hv = *(const f16x8*)(&h_lds[p][(c * 64 + lane) * 8]);
            const f16x2 h0 = { hv[0], hv[1] }, h1 = { hv[2], hv[3] };
            const f16x2 h2 = { hv[4], hv[5] }, h3 = { hv[6], hv[7] };
            {
                const f16x2 w0 = { wreg0[c][0], wreg0[c][1] }, w1 = { wreg0[c][2], wreg0[c][3] };
                const f16x2 w2 = { wreg0[c][4], wreg0[c][5] }, w3 = { wreg0[c][6], wreg0[c][7] };
                a00 = __builtin_amdgcn_fdot2(w0, h0, a00, false);
                a01 = __builtin_amdgcn_fdot2(w1, h1, a01, false);
                a02 = __builtin_amdgcn_fdot2(w2, h2, a02, false);
                a03 = __builtin_amdgcn_fdot2(w3, h3, a03, false);
            }
            {
                const f16x2 w0 = { wreg1[c][0], wreg1[c][1] }, w1 = { wreg1[c][2], wreg1[c][3] };
                const f16x2 w2 = { wreg1[c][4], wreg1[c][5] }, w3 = { wreg1[c][6], wreg1[c][7] };
                a10 = __builtin_amdgcn_fdot2(w0, h0, a10, false);
                a11 = __builtin_amdgcn_fdot2(w1, h1, a11, false);
                a12 = __builtin_amdgcn_fdot2(w2, h2, a12, false);
                a13 = __builtin_amdgcn_fdot2(w3, h3, a13, false);
            }
        }
        float acc0 = (a00 + a01) + (a02 + a03);
        float acc1 = (a10 + a11) + (a12 + a13);
        {
            const f32x4 xf = *(const f32x4*)(&x_lds[p][lane * 4]);
            acc0 = fmaf(winreg0.x, xf.x, acc0); acc0 = fmaf(winreg0.y, xf.y, acc0);
            acc0 = fmaf(winreg0.z, xf.z, acc0); acc0 = fmaf(winreg0.w, xf.w, acc0);
            acc1 = fmaf(winreg1.x, xf.x, acc1); acc1 = fmaf(winreg1.y, xf.y, acc1);
            acc1 = fmaf(winreg1.z, xf.z, acc1); acc1 = fmaf(winreg1.w, xf.w, acc1);
        }
#pragma unroll
        for (int off = 32; off > 0; off >>= 1) {
            acc0 += __shfl_xor(acc0, off, 64);
            acc1 += __shfl_xor(acc1, off, 64);
        }

        // ---- tagged LDS relay: lanes 0,1 post rows 2w,2w+1 ----
        {
            const float v = (lane == 0) ? acc0 : acc1;
            if (lane < 2) {
                f16 hf = (f16)tanhf(v);
                u16 bits;
                __builtin_memcpy(&bits, &hf, 2);
                __hip_atomic_store(&red_tag[wave * 2 + lane],
                                   ((u32)(t + 1) << 16) | (u32)bits,
                                   __ATOMIC_RELAXED, __HIP_MEMORY_SCOPE_WORKGROUP);
            }
        }

        // ---- wave 15: gather 32 relay words, pack 16 granules, ONE burst ----
        if (wave == WPB - 1) {
            u32 myw = 0;
            if (lane < RPB) {
                do {
                    myw = __hip_atomic_load(&red_tag[lane], __ATOMIC_RELAXED,
                                            __HIP_MEMORY_SCOPE_WORKGROUP);
                } while ((myw >> 16) != (u32)(t + 1));
            }
            const u32 wa = (u32)__shfl((int)myw, lane * 2,     64);
            const u32 wb = (u32)__shfl((int)myw, lane * 2 + 1, 64);
            if (lane < GPB) {
                const u64 g = ((u64)(u32)(t + 1) << 48)
                            | ((u64)(wb & 0xffffu) << 16)
                            | ((u64)(wa & 0xffffu));
                __hip_atomic_store(g_out + b * GPB + lane, g,
                                   __ATOMIC_RELAXED, __HIP_MEMORY_SCOPE_AGENT);
            }
        }
        // no trailing barrier: next poll + parity LDS double-buffer gate reuse
    }

    // ---- epilogue: poll h_T (tag = T_STEPS, parity 0), 2 outputs/block ----
    {
        const u64* gp = hg0 + (size_t)tid * 2;
        const u64 tt = (u64)(u32)T_STEPS;
        u64 g0, g1;
        for (;;) {
            g0 = __hip_atomic_load(gp,     __ATOMIC_RELAXED, __HIP_MEMORY_SCOPE_AGENT);
            g1 = __hip_atomic_load(gp + 1, __ATOMIC_RELAXED, __HIP_MEMORY_SCOPE_AGENT);
            if (((g0 >> 48) == tt) & ((g1 >> 48) == tt)) break;
            __builtin_amdgcn_s_sleep(1);
        }
        u32* hl = (u32*)h_lds[0];
        hl[tid * 2 + 0] = (u32)g0;
        hl[tid * 2 + 1] = (u32)g1;
    }
    __syncthreads();
#pragma unroll
    for (int oj = 0; oj < 2; ++oj) {
        const int j = b * 2 + oj;
        const float* worow = Wout + (size_t)j * R;
        const f32x4 wv = *(const f32x4*)(worow + tid * 4);
        const f16* hf = h_lds[0];
        float acc = wv.x * (float)hf[tid * 4 + 0]
                  + wv.y * (float)hf[tid * 4 + 1]
                  + wv.z * (float)hf[tid * 4 + 2]
                  + wv.w * (float)hf[tid * 4 + 3];
#pragma unroll
        for (int off = 32; off > 0; off >>= 1)
            acc += __shfl_xor(acc, off, 64);
        if (lane == 0) red_f[wave] = acc;
        __syncthreads();
        if (tid == 0) {
            float s = bias[j];
#pragma unroll
            for (int w = 0; w < WPB; ++w) s += red_f[w];
            out[j] = s;
        }
        __syncthreads();  // red_f reuse guard for oj=1
    }
}

extern "C" void kernel_launch(void* const* d_in, const int* in_sizes, int n_in,
                              void* d_out, int out_size, void* d_ws, size_t ws_size,
                              hipStream_t stream) {
    const float* x    = (const float*)d_in[0];
    const float* Win  = (const float*)d_in[1];
    const float* W    = (const float*)d_in[2];
    const float* Wout = (const float*)d_in[3];
    const float* bias = (const float*)d_in[4];
    float* out = (float*)d_out;

    char* ws = (char*)d_ws;
    u64* hg0 = (u64*)ws;                   // 16 KB tagged granules, parity 0
    u64* hg1 = (u64*)(ws + 16384);         // 16 KB tagged granules, parity 1
    f16* Wh  = (f16*)(ws + 65536);         // 32 MB fp16 W

    // zero both granule buffers: h_0 = 0 with tag 0 comes for free
    hipMemsetAsync(ws, 0, 65536, stream);

    wconv_kernel<<<(R * (size_t)R) / (256 * 4), 256, 0, stream>>>(W, Wh);
    esn_kernel<<<NBLK, TPB, 0, stream>>>(x, Win, Wh, hg0, hg1,
                                         Wout, bias, out);
}